// Round 3
// baseline (706.778 us; speedup 1.0000x reference)
//
#include <hip/hip_runtime.h>
#include <stdint.h>

typedef unsigned long long ull;

#define NPGC 512
#define EPGC 4096
#define NTHREADS 512
#define ETOT 4194304
#define NEGF (-1e30f)

union SortRed {
    ull key[NPGC];                                    // 4096 B: score keys
    struct { float r1[8][64]; float r2[8][64]; } red; // 4096 B: attention reduce
};

__global__ __launch_bounds__(NTHREADS, 8)
void gce_kernel(const float* __restrict__ x,
                const float* __restrict__ Wc,
                const float* __restrict__ bc,
                const float* __restrict__ pvec,
                const float* __restrict__ Wg,
                const float* __restrict__ bg,
                const int* __restrict__ ei,
                float* __restrict__ out)
{
    __shared__ float X[8][NPGC];    // 16 KB current features (channel-major)
    __shared__ float Y[8][NPGC];    // 16 KB h @ W
    __shared__ float maskf[NPGC];   //  2 KB
    __shared__ float degv[NPGC];    //  2 KB deg/dinv; later comp16[512]+chanmax[64]
    __shared__ SortRed u;           //  4 KB
    // total exactly 40960 B -> 4 blocks/CU x 8 waves = 32 waves/CU (100%)

    const int tid = threadIdx.x;
    const int g   = blockIdx.x;
    const int c   = tid & 63;       // attention channel
    const int grp = tid >> 6;       // wave id (0..7)

    unsigned short* comp16 = reinterpret_cast<unsigned short*>(degv); // bytes [0,1024)
    float* chmax = degv + 256;                                        // bytes [1024,1280)

    // per-thread Wg column + bias (registers for whole kernel)
    float wgc[8];
#pragma unroll
    for (int j = 0; j < 8; ++j) wgc[j] = Wg[j * 64 + c];
    const float bgc = bg[c];

    // ---- preload this thread's 8 edges, packed (row | col<<16), local ids
    uint32_t er[8];
    {
        const int* rowp = ei;
        const int* colp = ei + ETOT;
        const size_t eb = (size_t)g * EPGC + (size_t)tid * 8;
#pragma unroll
        for (int i = 0; i < 2; ++i) {
            int4 r4 = *reinterpret_cast<const int4*>(rowp + eb + i * 4);
            int4 c4 = *reinterpret_cast<const int4*>(colp + eb + i * 4);
            er[i * 4 + 0] = (uint32_t)(r4.x & 511) | ((uint32_t)(c4.x & 511) << 16);
            er[i * 4 + 1] = (uint32_t)(r4.y & 511) | ((uint32_t)(c4.y & 511) << 16);
            er[i * 4 + 2] = (uint32_t)(r4.z & 511) | ((uint32_t)(c4.z & 511) << 16);
            er[i * 4 + 3] = (uint32_t)(r4.w & 511) | ((uint32_t)(c4.w & 511) << 16);
        }
    }

    // ---- load x into X (transpose to channel-major), mask = 1
    {
        const int n = tid;
        const float* xr = x + ((size_t)g * NPGC + n) * 8;
        float4 a = *reinterpret_cast<const float4*>(xr);
        float4 b = *reinterpret_cast<const float4*>(xr + 4);
        X[0][n] = a.x; X[1][n] = a.y; X[2][n] = a.z; X[3][n] = a.w;
        X[4][n] = b.x; X[5][n] = b.y; X[6][n] = b.z; X[7][n] = b.w;
        maskf[n] = 1.0f;
    }

    float out_acc = 0.0f;

#pragma unroll 1
    for (int layer = 0; layer < 4; ++layer) {
        const float* Wl = Wc + layer * 64;
        const float* bl = bc + layer * 8;
        const float* pl = pvec + layer * 8;
        const int kk = (layer == 0) ? 410 : (layer == 1) ? 328 : (layer == 2) ? 263 : 211;

        __syncthreads();                  // X/maskf ready; degv (comp/chmax) dead
        degv[tid] = maskf[tid];
        __syncthreads();

        // ---- phase 1: Y = X @ W (valid nodes) + degree atomics
        {
            const int n = tid;
            if (maskf[n] > 0.f) {
                float hv[8];
#pragma unroll
                for (int j = 0; j < 8; ++j) hv[j] = X[j][n];
#pragma unroll
                for (int k = 0; k < 8; ++k) {
                    float acc = 0.f;
#pragma unroll
                    for (int j = 0; j < 8; ++j) acc += hv[j] * Wl[j * 8 + k];
                    Y[k][n] = acc;
                }
            }
        }
#pragma unroll
        for (int i = 0; i < 8; ++i) {
            const int rl = er[i] & 0xffff, cl = er[i] >> 16;
            if (maskf[rl] > 0.f && maskf[cl] > 0.f)
                atomicAdd(&degv[cl], 1.0f);
        }
        __syncthreads();

        // ---- phase 2: dinv = deg^-0.5 (0 for invalid) ; X = self-loop term
        {
            const int n = tid;
            const float dg = degv[n];
            const float di = (dg > 0.f) ? rsqrtf(dg) : 0.f;
            degv[n] = di;                 // own slot: no race
            if (maskf[n] > 0.f) {
                const float c0 = di * di;
#pragma unroll
                for (int k = 0; k < 8; ++k) X[k][n] = Y[k][n] * c0;
            }
        }
        __syncthreads();

        // ---- phase 3: edge scatter  X[:,col] += Y[:,row] * dinv[row]*dinv[col]
#pragma unroll
        for (int i = 0; i < 8; ++i) {
            const int rl = er[i] & 0xffff, cl = er[i] >> 16;
            const float nrm = degv[rl] * degv[cl];   // 0 unless both valid
            if (nrm > 0.f) {
#pragma unroll
                for (int k = 0; k < 8; ++k)
                    atomicAdd(&X[k][cl], Y[k][rl] * nrm);
            }
        }
        __syncthreads();

        // ---- phase 4: (+bias)*mask, relu, score, sort key (key kept in regs)
        float s0;
        ull key0;
        {
            float pv[8], ss = 0.f;
#pragma unroll
            for (int k = 0; k < 8; ++k) { pv[k] = pl[k]; ss += pv[k] * pv[k]; }
            const float pn = sqrtf(ss);
            const int n = tid;
            const float mf = maskf[n];
            float dot = 0.f;
#pragma unroll
            for (int k = 0; k < 8; ++k) {
                float v = (X[k][n] + bl[k]) * mf;
                v = fmaxf(v, 0.f);
                X[k][n] = v;
                dot += v * pv[k];
            }
            s0 = tanhf(dot / pn);
            const float sm = (mf > 0.f) ? s0 : NEGF;
            const unsigned ub  = __float_as_uint(sm);
            const unsigned asc = (ub & 0x80000000u) ? ~ub : (ub | 0x80000000u);
            key0 = ((ull)(~asc) << 32) | (unsigned)n;
            u.key[n] = key0;
        }
        __syncthreads();

        // ---- phase 5: rank by counting (broadcast reads, branch-free)
        int r0 = 0;
#pragma unroll 8
        for (int j = 0; j < NPGC; j += 2) {
            const ull ka = u.key[j];
            const ull kb = u.key[j + 1];
            r0 += (int)(ka < key0) + (int)(kb < key0);
        }
        // masked nodes carry maximal keys -> rank >= n_valid >= kk, never kept.

        // ---- phase 6: keep top-k, scale X, build compacted list (own slot only)
        {
            const int n = tid;
            if (r0 < kk) {
                comp16[r0] = (unsigned short)n;
#pragma unroll
                for (int k = 0; k < 8; ++k) X[k][n] *= s0;
            } else {
                maskf[n] = 0.f;
#pragma unroll
                for (int k = 0; k < 8; ++k) X[k][n] = 0.f;
            }
        }
        __syncthreads();

        // ---- phase 7: attention pool over compacted valid list (2-way ILP)
        {
            float mloc = NEGF;
            int i = grp;
            for (; i + 8 < kk; i += 16) {
                const int na = comp16[i];
                const int nb = comp16[i + 8];
                float ga = bgc, gb = bgc;
#pragma unroll
                for (int j = 0; j < 8; ++j) {
                    ga += X[j][na] * wgc[j];   // LDS broadcast reads
                    gb += X[j][nb] * wgc[j];
                }
                mloc = fmaxf(mloc, fmaxf(ga, gb));
            }
            if (i < kk) {
                const int na = comp16[i];
                float ga = bgc;
#pragma unroll
                for (int j = 0; j < 8; ++j) ga += X[j][na] * wgc[j];
                mloc = fmaxf(mloc, ga);
            }
            u.red.r1[grp][c] = mloc;
            __syncthreads();
            if (tid < 64) {
                float m = u.red.r1[0][tid];
#pragma unroll
                for (int w = 1; w < 8; ++w) m = fmaxf(m, u.red.r1[w][tid]);
                chmax[tid] = m;
            }
            __syncthreads();
            const float mc = chmax[c];

            float esum = 0.f, wsum = 0.f;
            i = grp;
            for (; i + 8 < kk; i += 16) {
                const int na = comp16[i];
                const int nb = comp16[i + 8];
                float ga = bgc, gb = bgc;
#pragma unroll
                for (int j = 0; j < 8; ++j) {
                    ga += X[j][na] * wgc[j];
                    gb += X[j][nb] * wgc[j];
                }
                const float ea = __expf(ga - mc);
                const float eb2 = __expf(gb - mc);
                esum += ea + eb2;
                wsum += ea * ga + eb2 * gb;
            }
            if (i < kk) {
                const int na = comp16[i];
                float ga = bgc;
#pragma unroll
                for (int j = 0; j < 8; ++j) ga += X[j][na] * wgc[j];
                const float ea = __expf(ga - mc);
                esum += ea;
                wsum += ea * ga;
            }
            u.red.r1[grp][c] = esum;
            u.red.r2[grp][c] = wsum;
            __syncthreads();
            if (tid < 64) {
                float es = 0.f, ws = 0.f;
#pragma unroll
                for (int w = 0; w < 8; ++w) { es += u.red.r1[w][tid]; ws += u.red.r2[w][tid]; }
                out_acc += ws / es;
            }
        }
    }

    if (tid < 64) out[(size_t)g * 64 + tid] = out_acc;
}

extern "C" void kernel_launch(void* const* d_in, const int* in_sizes, int n_in,
                              void* d_out, int out_size, void* d_ws, size_t ws_size,
                              hipStream_t stream) {
    const float* x    = (const float*)d_in[0];
    const float* Wc   = (const float*)d_in[1];
    const float* bc   = (const float*)d_in[2];
    const float* pvec = (const float*)d_in[3];
    const float* Wg   = (const float*)d_in[4];
    const float* bg   = (const float*)d_in[5];
    const int*   ei   = (const int*)d_in[6];
    float* out = (float*)d_out;

    gce_kernel<<<dim3(1024), dim3(NTHREADS), 0, stream>>>(x, Wc, bc, pvec, Wg, bg, ei, out);
}

// Round 4
// 683.050 us; speedup vs baseline: 1.0347x; 1.0347x over previous
//
#include <hip/hip_runtime.h>
#include <stdint.h>

typedef unsigned long long ull;

#define NPGC 512
#define EPGC 4096
#define NTHREADS 512
#define ETOT 4194304
#define NEGF (-1e30f)

union SortRed {
    ull key[NPGC];                                    // 4096 B: score keys
    struct { float r1[8][64]; float r2[8][64]; } red; // 4096 B: attention reduce
};

__global__ __launch_bounds__(NTHREADS, 6)
void gce_kernel(const float* __restrict__ x,
                const float* __restrict__ Wc,
                const float* __restrict__ bc,
                const float* __restrict__ pvec,
                const float* __restrict__ Wg,
                const float* __restrict__ bg,
                const int* __restrict__ ei,
                float* __restrict__ out)
{
    __shared__ float X[8][NPGC];    // 16 KB current features (channel-major)
    __shared__ float Y[8][NPGC];    // 16 KB h @ W
    __shared__ float maskf[NPGC];   //  2 KB
    __shared__ float degv[NPGC];    //  2 KB deg/dinv; later comp16[512]+chanmax[64]
    __shared__ SortRed u;           //  4 KB
    // total exactly 40960 B -> LDS allows 4 blocks/CU (32 waves/CU)

    const int tid = threadIdx.x;
    const int g   = blockIdx.x;
    const int c   = tid & 63;       // attention channel
    const int grp = tid >> 6;       // wave id (0..7)

    unsigned short* comp16 = reinterpret_cast<unsigned short*>(degv); // bytes [0,1024)
    float* chmax = degv + 256;                                        // bytes [1024,1280)

    // per-thread Wg column + bias (registers for whole kernel)
    float wgc[8];
#pragma unroll
    for (int j = 0; j < 8; ++j) wgc[j] = Wg[j * 64 + c];
    const float bgc = bg[c];

    // ---- preload this thread's 8 edges, packed (row | col<<16), local ids
    uint32_t er[8];
    {
        const int* rowp = ei;
        const int* colp = ei + ETOT;
        const size_t eb = (size_t)g * EPGC + (size_t)tid * 8;
#pragma unroll
        for (int i = 0; i < 2; ++i) {
            int4 r4 = *reinterpret_cast<const int4*>(rowp + eb + i * 4);
            int4 c4 = *reinterpret_cast<const int4*>(colp + eb + i * 4);
            er[i * 4 + 0] = (uint32_t)(r4.x & 511) | ((uint32_t)(c4.x & 511) << 16);
            er[i * 4 + 1] = (uint32_t)(r4.y & 511) | ((uint32_t)(c4.y & 511) << 16);
            er[i * 4 + 2] = (uint32_t)(r4.z & 511) | ((uint32_t)(c4.z & 511) << 16);
            er[i * 4 + 3] = (uint32_t)(r4.w & 511) | ((uint32_t)(c4.w & 511) << 16);
        }
    }

    // ---- load x into X (transpose to channel-major), mask = 1
    {
        const int n = tid;
        const float* xr = x + ((size_t)g * NPGC + n) * 8;
        float4 a = *reinterpret_cast<const float4*>(xr);
        float4 b = *reinterpret_cast<const float4*>(xr + 4);
        X[0][n] = a.x; X[1][n] = a.y; X[2][n] = a.z; X[3][n] = a.w;
        X[4][n] = b.x; X[5][n] = b.y; X[6][n] = b.z; X[7][n] = b.w;
        maskf[n] = 1.0f;
    }

    float out_acc = 0.0f;

#pragma unroll 1
    for (int layer = 0; layer < 4; ++layer) {
        const float* Wl = Wc + layer * 64;
        const float* bl = bc + layer * 8;
        const float* pl = pvec + layer * 8;
        const int kk = (layer == 0) ? 410 : (layer == 1) ? 328 : (layer == 2) ? 263 : 211;

        __syncthreads();                  // X/maskf ready; degv (comp/chmax) dead
        degv[tid] = maskf[tid];
        __syncthreads();

        // ---- phase 1: Y = X @ W (valid nodes) + degree atomics
        {
            const int n = tid;
            if (maskf[n] > 0.f) {
                float hv[8];
#pragma unroll
                for (int j = 0; j < 8; ++j) hv[j] = X[j][n];
#pragma unroll
                for (int k = 0; k < 8; ++k) {
                    float acc = 0.f;
#pragma unroll
                    for (int j = 0; j < 8; ++j) acc += hv[j] * Wl[j * 8 + k];
                    Y[k][n] = acc;
                }
            }
        }
#pragma unroll
        for (int i = 0; i < 8; ++i) {
            const int rl = er[i] & 0xffff, cl = er[i] >> 16;
            if (maskf[rl] > 0.f && maskf[cl] > 0.f)
                atomicAdd(&degv[cl], 1.0f);
        }
        __syncthreads();

        // ---- phase 2: dinv = deg^-0.5 (0 for invalid) ; X = self-loop term
        {
            const int n = tid;
            const float dg = degv[n];
            const float di = (dg > 0.f) ? rsqrtf(dg) : 0.f;
            degv[n] = di;                 // own slot: no race
            if (maskf[n] > 0.f) {
                const float c0 = di * di;
#pragma unroll
                for (int k = 0; k < 8; ++k) X[k][n] = Y[k][n] * c0;
            }
        }
        __syncthreads();

        // ---- phase 3: edge scatter  X[:,col] += Y[:,row] * dinv[row]*dinv[col]
#pragma unroll
        for (int i = 0; i < 8; ++i) {
            const int rl = er[i] & 0xffff, cl = er[i] >> 16;
            const float nrm = degv[rl] * degv[cl];   // 0 unless both valid
            if (nrm > 0.f) {
#pragma unroll
                for (int k = 0; k < 8; ++k)
                    atomicAdd(&X[k][cl], Y[k][rl] * nrm);
            }
        }
        __syncthreads();

        // ---- phase 4: (+bias)*mask, relu, score, sort key (key kept in regs)
        float s0;
        ull key0;
        {
            float pv[8], ss = 0.f;
#pragma unroll
            for (int k = 0; k < 8; ++k) { pv[k] = pl[k]; ss += pv[k] * pv[k]; }
            const float pn = sqrtf(ss);
            const int n = tid;
            const float mf = maskf[n];
            float dot = 0.f;
#pragma unroll
            for (int k = 0; k < 8; ++k) {
                float v = (X[k][n] + bl[k]) * mf;
                v = fmaxf(v, 0.f);
                X[k][n] = v;
                dot += v * pv[k];
            }
            s0 = tanhf(dot / pn);
            const float sm = (mf > 0.f) ? s0 : NEGF;
            const unsigned ub  = __float_as_uint(sm);
            const unsigned asc = (ub & 0x80000000u) ? ~ub : (ub | 0x80000000u);
            key0 = ((ull)(~asc) << 32) | (unsigned)n;
            u.key[n] = key0;
        }
        __syncthreads();

        // ---- phase 5: rank by counting (broadcast reads, branch-free)
        int r0 = 0;
#pragma unroll 4
        for (int j = 0; j < NPGC; j += 2) {
            const ull ka = u.key[j];
            const ull kb = u.key[j + 1];
            r0 += (int)(ka < key0) + (int)(kb < key0);
        }
        // masked nodes carry maximal keys -> rank >= n_valid >= kk, never kept.

        // ---- phase 6: keep top-k, scale X, build compacted list (own slot only)
        {
            const int n = tid;
            if (r0 < kk) {
                comp16[r0] = (unsigned short)n;
#pragma unroll
                for (int k = 0; k < 8; ++k) X[k][n] *= s0;
            } else {
                maskf[n] = 0.f;
#pragma unroll
                for (int k = 0; k < 8; ++k) X[k][n] = 0.f;
            }
        }
        __syncthreads();

        // ---- phase 7: attention pool, single-pass online softmax per (grp,c)
        {
            float m = NEGF, esum = 0.f, wsum = 0.f;
            for (int i = grp; i < kk; i += 8) {
                const int n = comp16[i];            // wave-uniform
                float gv = bgc;
#pragma unroll
                for (int j = 0; j < 8; ++j) gv += X[j][n] * wgc[j];  // LDS broadcast
                const float mn = fmaxf(m, gv);
                const float sc = __expf(m - mn);    // first iter: exp(-inf)=0
                const float e  = __expf(gv - mn);
                esum = esum * sc + e;
                wsum = wsum * sc + e * gv;
                m = mn;
            }
            u.red.r1[grp][c] = m;
            __syncthreads();
            if (tid < 64) {
                float M = u.red.r1[0][tid];
#pragma unroll
                for (int w = 1; w < 8; ++w) M = fmaxf(M, u.red.r1[w][tid]);
                chmax[tid] = M;
            }
            __syncthreads();
            const float M = chmax[c];
            const float sc = __expf(m - M);
            u.red.r1[grp][c] = esum * sc;
            u.red.r2[grp][c] = wsum * sc;
            __syncthreads();
            if (tid < 64) {
                float es = 0.f, ws = 0.f;
#pragma unroll
                for (int w = 0; w < 8; ++w) { es += u.red.r1[w][tid]; ws += u.red.r2[w][tid]; }
                out_acc += ws / es;
            }
        }
    }

    if (tid < 64) out[(size_t)g * 64 + tid] = out_acc;
}

extern "C" void kernel_launch(void* const* d_in, const int* in_sizes, int n_in,
                              void* d_out, int out_size, void* d_ws, size_t ws_size,
                              hipStream_t stream) {
    const float* x    = (const float*)d_in[0];
    const float* Wc   = (const float*)d_in[1];
    const float* bc   = (const float*)d_in[2];
    const float* pvec = (const float*)d_in[3];
    const float* Wg   = (const float*)d_in[4];
    const float* bg   = (const float*)d_in[5];
    const int*   ei   = (const int*)d_in[6];
    float* out = (float*)d_out;

    gce_kernel<<<dim3(1024), dim3(NTHREADS), 0, stream>>>(x, Wc, bc, pvec, Wg, bg, ei, out);
}

// Round 5
// 573.937 us; speedup vs baseline: 1.2315x; 1.1901x over previous
//
#include <hip/hip_runtime.h>
#include <stdint.h>

typedef unsigned long long ull;

#define NPGC 512
#define EPGC 4096
#define NTHREADS 512
#define ETOT 4194304
#define NEGF (-1e30f)

__global__ __launch_bounds__(NTHREADS, 6)
void gce_kernel(const float* __restrict__ x,
                const float* __restrict__ Wc,
                const float* __restrict__ bc,
                const float* __restrict__ pvec,
                const float* __restrict__ Wg,
                const float* __restrict__ bg,
                const int* __restrict__ ei,
                float* __restrict__ out)
{
    __shared__ float  A[8][NPGC];              // 16 KB channel-major conv accumulator (atomic target)
    __shared__ float4 Blo[NPGC];               //  8 KB node-major features ch 0-3
    __shared__ float4 Bhi[NPGC];               //  8 KB node-major features ch 4-7
    __shared__ float  maskf[NPGC];             //  2 KB
    __shared__ float  degv[NPGC];              //  2 KB deg->dinv; later comp16[512]+chmax[64]
    __shared__ __align__(16) ull keyv[NPGC];   //  4 KB rank keys; later r1/r2 reduce
    // total exactly 40960 B -> 4 blocks/CU

    const int tid = threadIdx.x;
    const int g   = blockIdx.x;
    const int c   = tid & 63;        // attention channel
    const int grp = tid >> 6;        // wave id (0..7)

    unsigned short* comp16 = reinterpret_cast<unsigned short*>(degv);  // bytes [0,1024)
    float* chmax = degv + 256;                                         // bytes [1024,1280)
    float* r1 = reinterpret_cast<float*>(keyv);                        // [8][64] = 2 KB
    float* r2 = r1 + 512;                                              // [8][64] = 2 KB

    float wgc[8];
#pragma unroll
    for (int j = 0; j < 8; ++j) wgc[j] = Wg[j * 64 + c];
    const float bgc = bg[c];

    // ---- preload this thread's 8 edges, packed (row | col<<16), local ids
    uint32_t er[8];
    {
        const int* rowp = ei;
        const int* colp = ei + ETOT;
        const size_t eb = (size_t)g * EPGC + (size_t)tid * 8;
#pragma unroll
        for (int i = 0; i < 2; ++i) {
            int4 r4 = *reinterpret_cast<const int4*>(rowp + eb + i * 4);
            int4 c4 = *reinterpret_cast<const int4*>(colp + eb + i * 4);
            er[i * 4 + 0] = (uint32_t)(r4.x & 511) | ((uint32_t)(c4.x & 511) << 16);
            er[i * 4 + 1] = (uint32_t)(r4.y & 511) | ((uint32_t)(c4.y & 511) << 16);
            er[i * 4 + 2] = (uint32_t)(r4.z & 511) | ((uint32_t)(c4.z & 511) << 16);
            er[i * 4 + 3] = (uint32_t)(r4.w & 511) | ((uint32_t)(c4.w & 511) << 16);
        }
    }

    // ---- load x into node-major B, mask = 1
    {
        const float* xr = x + ((size_t)g * NPGC + tid) * 8;
        Blo[tid] = *reinterpret_cast<const float4*>(xr);
        Bhi[tid] = *reinterpret_cast<const float4*>(xr + 4);
        maskf[tid] = 1.0f;
    }

    int   rprev  = tid;     // slot of this node's key in keyv (rank from prev layer)
    int   kkprev = NPGC;    // number of valid nodes entering this layer
    float out_acc = 0.f;

#pragma unroll 1
    for (int layer = 0; layer < 4; ++layer) {
        const float* Wl = Wc + layer * 64;
        const float* bl = bc + layer * 8;
        const float* pl = pvec + layer * 8;
        const int kk = (layer == 0) ? 410 : (layer == 1) ? 328 : (layer == 2) ? 263 : 211;

        __syncthreads();                 // B/maskf ready; degv/keyv regions free
        const float mf = maskf[tid];
        degv[tid] = mf;
        __syncthreads();

        // ---- P1: B <- B @ W (in place, own slot) ; degree atomics
        if (mf > 0.f) {
            const float4 lo = Blo[tid], hi = Bhi[tid];
            const float hv[8] = {lo.x, lo.y, lo.z, lo.w, hi.x, hi.y, hi.z, hi.w};
            float yv[8];
#pragma unroll
            for (int k = 0; k < 8; ++k) {
                float acc = 0.f;
#pragma unroll
                for (int j = 0; j < 8; ++j) acc += hv[j] * Wl[j * 8 + k];
                yv[k] = acc;
            }
            Blo[tid] = make_float4(yv[0], yv[1], yv[2], yv[3]);
            Bhi[tid] = make_float4(yv[4], yv[5], yv[6], yv[7]);
        }
#pragma unroll
        for (int i = 0; i < 8; ++i) {
            const int rl = er[i] & 0xffff, cl = er[i] >> 16;
            if (maskf[rl] > 0.f && maskf[cl] > 0.f)
                atomicAdd(&degv[cl], 1.0f);
        }
        __syncthreads();

        // ---- P2: dinv ; A <- self-loop term (valid nodes)
        {
            const float dg = degv[tid];
            const float di = (dg > 0.f) ? rsqrtf(dg) : 0.f;
            degv[tid] = di;              // own slot
            if (mf > 0.f) {
                const float c0 = di * di;
                const float4 lo = Blo[tid], hi = Bhi[tid];
                A[0][tid] = lo.x * c0; A[1][tid] = lo.y * c0;
                A[2][tid] = lo.z * c0; A[3][tid] = lo.w * c0;
                A[4][tid] = hi.x * c0; A[5][tid] = hi.y * c0;
                A[6][tid] = hi.z * c0; A[7][tid] = hi.w * c0;
            }
        }
        __syncthreads();

        // ---- P3: edge scatter  A[:,col] += B[row] * dinv[row]*dinv[col]
#pragma unroll
        for (int i = 0; i < 8; ++i) {
            const int rl = er[i] & 0xffff, cl = er[i] >> 16;
            const float nrm = degv[rl] * degv[cl];   // 0 unless both valid
            if (nrm > 0.f) {
                const float4 lo = Blo[rl], hi = Bhi[rl];   // 2 x b128 gather
                atomicAdd(&A[0][cl], lo.x * nrm);
                atomicAdd(&A[1][cl], lo.y * nrm);
                atomicAdd(&A[2][cl], lo.z * nrm);
                atomicAdd(&A[3][cl], lo.w * nrm);
                atomicAdd(&A[4][cl], hi.x * nrm);
                atomicAdd(&A[5][cl], hi.y * nrm);
                atomicAdd(&A[6][cl], hi.z * nrm);
                atomicAdd(&A[7][cl], hi.w * nrm);
            }
        }
        __syncthreads();

        // ---- P4: (+bias)*mask, relu -> B ; score ; key -> compacted slot
        float s0;
        ull key0;
        {
            float pv[8], ss = 0.f;
#pragma unroll
            for (int k = 0; k < 8; ++k) { pv[k] = pl[k]; ss += pv[k] * pv[k]; }
            const float pn = sqrtf(ss);
            float v[8], dot = 0.f;
#pragma unroll
            for (int k = 0; k < 8; ++k) {
                float t = (A[k][tid] + bl[k]) * mf;
                t = fmaxf(t, 0.f);
                v[k] = t;
                dot += t * pv[k];
            }
            Blo[tid] = make_float4(v[0], v[1], v[2], v[3]);
            Bhi[tid] = make_float4(v[4], v[5], v[6], v[7]);
            s0 = tanhf(dot / pn);
            const unsigned ub  = __float_as_uint(s0);
            const unsigned asc = (ub & 0x80000000u) ? ~ub : (ub | 0x80000000u);
            key0 = ((ull)(~asc) << 32) | (unsigned)tid;
            if (mf > 0.f) keyv[rprev] = key0;      // compacted: slots [0,kkprev)
        }
        if (tid == 0 && kkprev < NPGC) keyv[kkprev] = ~0ull;  // pad for b128 pair read
        __syncthreads();

        // ---- P5: rank by counting over compacted keys (b128 = 2 keys/read)
        int r0 = 0;
        {
            const int bound = (kkprev + 1) & ~1;
#pragma unroll 4
            for (int j = 0; j < bound; j += 2) {
                const ulonglong2 kv = *reinterpret_cast<const ulonglong2*>(&keyv[j]);
                r0 += (int)(kv.x < key0) + (int)(kv.y < key0);
            }
        }

        // ---- P6: keep top-k, scale B by s, build compacted node list
        {
            const bool keep = (mf > 0.f) && (r0 < kk);
            if (keep) {
                comp16[r0] = (unsigned short)tid;
                float4 lo = Blo[tid], hi = Bhi[tid];
                lo.x *= s0; lo.y *= s0; lo.z *= s0; lo.w *= s0;
                hi.x *= s0; hi.y *= s0; hi.z *= s0; hi.w *= s0;
                Blo[tid] = lo; Bhi[tid] = hi;
            } else {
                maskf[tid] = 0.f;        // B self-heals to 0 next layer via mf
            }
            rprev = r0;
        }
        __syncthreads();

        // ---- P7: attention pool, online softmax, 2-way ILP, vector gate reads
        {
            float m = NEGF, esum = 0.f, wsum = 0.f;
            int i = grp;
            for (; i + 8 < kk; i += 16) {
                const int na = comp16[i];
                const int nb = comp16[i + 8];
                const float4 alo = Blo[na], ahi = Bhi[na];   // broadcast b128
                const float4 blo = Blo[nb], bhi = Bhi[nb];
                float ga = bgc, gb = bgc;
                ga += alo.x * wgc[0] + alo.y * wgc[1] + alo.z * wgc[2] + alo.w * wgc[3];
                ga += ahi.x * wgc[4] + ahi.y * wgc[5] + ahi.z * wgc[6] + ahi.w * wgc[7];
                gb += blo.x * wgc[0] + blo.y * wgc[1] + blo.z * wgc[2] + blo.w * wgc[3];
                gb += bhi.x * wgc[4] + bhi.y * wgc[5] + bhi.z * wgc[6] + bhi.w * wgc[7];
                const float mn = fmaxf(m, fmaxf(ga, gb));
                const float sc = __expf(m - mn);
                const float ea = __expf(ga - mn);
                const float eb = __expf(gb - mn);
                esum = esum * sc + ea + eb;
                wsum = wsum * sc + ea * ga + eb * gb;
                m = mn;
            }
            if (i < kk) {
                const int na = comp16[i];
                const float4 alo = Blo[na], ahi = Bhi[na];
                float ga = bgc;
                ga += alo.x * wgc[0] + alo.y * wgc[1] + alo.z * wgc[2] + alo.w * wgc[3];
                ga += ahi.x * wgc[4] + ahi.y * wgc[5] + ahi.z * wgc[6] + ahi.w * wgc[7];
                const float mn = fmaxf(m, ga);
                const float sc = __expf(m - mn);
                const float ea = __expf(ga - mn);
                esum = esum * sc + ea;
                wsum = wsum * sc + ea * ga;
                m = mn;
            }
            r1[grp * 64 + c] = m;
            __syncthreads();
            if (tid < 64) {
                float M = r1[tid];
#pragma unroll
                for (int w = 1; w < 8; ++w) M = fmaxf(M, r1[w * 64 + tid]);
                chmax[tid] = M;
            }
            __syncthreads();
            const float M  = chmax[c];
            const float sc = __expf(m - M);
            r1[grp * 64 + c] = esum * sc;
            r2[grp * 64 + c] = wsum * sc;
            __syncthreads();
            if (tid < 64) {
                float es = 0.f, ws = 0.f;
#pragma unroll
                for (int w = 0; w < 8; ++w) { es += r1[w * 64 + tid]; ws += r2[w * 64 + tid]; }
                out_acc += ws / es;
            }
        }

        kkprev = kk;
    }

    if (tid < 64) out[(size_t)g * 64 + tid] = out_acc;
}

extern "C" void kernel_launch(void* const* d_in, const int* in_sizes, int n_in,
                              void* d_out, int out_size, void* d_ws, size_t ws_size,
                              hipStream_t stream) {
    const float* x    = (const float*)d_in[0];
    const float* Wc   = (const float*)d_in[1];
    const float* bc   = (const float*)d_in[2];
    const float* pvec = (const float*)d_in[3];
    const float* Wg   = (const float*)d_in[4];
    const float* bg   = (const float*)d_in[5];
    const int*   ei   = (const int*)d_in[6];
    float* out = (float*)d_out;

    gce_kernel<<<dim3(1024), dim3(NTHREADS), 0, stream>>>(x, Wc, bc, pvec, Wg, bg, ei, out);
}